// Round 5
// baseline (225.758 us; speedup 1.0000x reference)
//
#include <hip/hip_runtime.h>

typedef unsigned short u16;
typedef __attribute__((ext_vector_type(8))) short bf16x8;
typedef __attribute__((ext_vector_type(4))) short bf16x4;
typedef __attribute__((ext_vector_type(4))) float f32x4;

#define NB 2
#define SEQ 2048
#define HID 1024
#define NHEAD 16
#define HD 64
#define MROWS (NB * SEQ) /* 4096 */

__device__ __forceinline__ u16 f2bf(float f) {
  union { float f; unsigned u; } x; x.f = f;
  unsigned r = x.u + 0x7fffu + ((x.u >> 16) & 1u);
  return (u16)(r >> 16);
}

#define GLOAD_LDS16(g, l)                                                   \
  __builtin_amdgcn_global_load_lds(                                         \
      (const __attribute__((address_space(1))) void*)(g),                   \
      (__attribute__((address_space(3))) void*)(l), 16, 0, 0)

// f32 -> bf16 elementwise, 8 elems/thread.
__global__ __launch_bounds__(256)
void conv_f32_bf16(const float* __restrict__ src, u16* __restrict__ dst, int nvec)
{
  const int i = blockIdx.x * 256 + threadIdx.x;
  if (i >= nvec) return;
  const float* s = src + (size_t)i * 8;
  f32x4 a = *(const f32x4*)s;
  f32x4 b = *(const f32x4*)(s + 4);
  bf16x8 o;
#pragma unroll
  for (int j = 0; j < 4; ++j) { o[j] = (short)f2bf(a[j]); o[4 + j] = (short)f2bf(b[j]); }
  *(bf16x8*)(dst + (size_t)i * 8) = o;
}

// C[m,n] = (sum_k A[m,k]*W[n,k] + bias[n]) * scale.  A,W bf16; bias f32.
// BM=64 BN=128 BK=32, 4 waves. 3-buffer LDS, counted-vmcnt single-barrier
// pipeline (T3+T4): raw s_barrier, vmcnt(3) in steady state, never drained
// until the last k-step.
// mode 0: bf16 split-head Out[b][h][n][d]
// mode 1: f32 row-major   Out[m][n]
// mode 2: bf16 transposed Out[b][h][d][n]   (for V)
__global__ __launch_bounds__(256)
void gemm_bf16(const u16* __restrict__ A, const u16* __restrict__ W,
               const float* __restrict__ bias, void* __restrict__ Out_,
               float scale, int mode)
{
  __shared__ u16 As[3 * 64 * 32];    // 12 KB (3 bufs)
  __shared__ u16 Bs[3 * 128 * 32];   // 24 KB
  const int n0 = blockIdx.x * 128;
  const int m0 = blockIdx.y * 64;
  const int t = threadIdx.x;
  const int lane = t & 63, w = t >> 6;
  const int grp = lane >> 4, lr = lane & 15;
  const int wr = (w >> 1) * 32;
  const int wc = (w & 1) * 64;

  f32x4 acc[2][4];
#pragma unroll
  for (int i = 0; i < 2; ++i)
#pragma unroll
    for (int j = 0; j < 4; ++j) acc[i][j] = (f32x4){0.f, 0.f, 0.f, 0.f};

  const int sr = lane >> 2, kc = (lane & 3) * 8;
  const u16* ag  = A + (size_t)(m0 + w * 16 + sr) * HID + kc;
  const u16* bg0 = W + (size_t)(n0 + w * 32 + sr) * HID + kc;
  const u16* bg1 = bg0 + (size_t)16 * HID;

#define GSTAGE(bi, k0)                                             \
  {                                                                \
    u16* al  = As + (bi) * 2048 + w * 512;                         \
    u16* bl0 = Bs + (bi) * 4096 + w * 1024;                        \
    GLOAD_LDS16(ag + (k0), al);                                    \
    GLOAD_LDS16(bg0 + (k0), bl0);                                  \
    GLOAD_LDS16(bg1 + (k0), bl0 + 512);                            \
  }

  GSTAGE(0, 0);
  GSTAGE(1, 32);

  for (int it = 0; it < 32; ++it) {
    if (it < 31) asm volatile("s_waitcnt vmcnt(3)" ::: "memory");
    else         asm volatile("s_waitcnt vmcnt(0)" ::: "memory");
    __builtin_amdgcn_s_barrier();
    __builtin_amdgcn_sched_barrier(0);
    asm volatile("" ::: "memory");
    if (it < 30) GSTAGE((it + 2) % 3, (it + 2) * 32);
    const u16* Ab = As + (it % 3) * 2048;
    const u16* Bb = Bs + (it % 3) * 4096;
    bf16x8 af[2], bf[4];
#pragma unroll
    for (int mi = 0; mi < 2; ++mi)
      af[mi] = *(const bf16x8*)&Ab[(wr + mi * 16 + lr) * 32 + grp * 8];
#pragma unroll
    for (int ni = 0; ni < 4; ++ni)
      bf[ni] = *(const bf16x8*)&Bb[(wc + ni * 16 + lr) * 32 + grp * 8];
    __builtin_amdgcn_s_setprio(1);
#pragma unroll
    for (int mi = 0; mi < 2; ++mi)
#pragma unroll
      for (int ni = 0; ni < 4; ++ni)
        acc[mi][ni] = __builtin_amdgcn_mfma_f32_16x16x32_bf16(
            af[mi], bf[ni], acc[mi][ni], 0, 0, 0);
    __builtin_amdgcn_s_setprio(0);
  }
#undef GSTAGE

#pragma unroll
  for (int mi = 0; mi < 2; ++mi) {
#pragma unroll
    for (int ni = 0; ni < 4; ++ni) {
      const int n = n0 + wc + ni * 16 + lr;
      const float bval = bias[n];
      const int mb = m0 + wr + mi * 16 + grp * 4;
      if (mode == 1) {
        float* O = (float*)Out_;
#pragma unroll
        for (int r = 0; r < 4; ++r)
          O[(size_t)(mb + r) * HID + n] = (acc[mi][ni][r] + bval) * scale;
      } else if (mode == 0) {
        u16* O = (u16*)Out_;
        const int h = n >> 6, d = n & (HD - 1);
#pragma unroll
        for (int r = 0; r < 4; ++r) {
          const int m = mb + r;
          const int b = m >> 11, nn = m & (SEQ - 1);
          O[((size_t)(b * NHEAD + h) * SEQ + nn) * HD + d] =
              f2bf((acc[mi][ni][r] + bval) * scale);
        }
      } else {  // mode 2: transposed V  Out[b][h][d][n]
        u16* O = (u16*)Out_;
        const int h = n >> 6, d = n & (HD - 1);
        const int b = mb >> 11, nn = mb & (SEQ - 1);
        bf16x4 pk;
#pragma unroll
        for (int r = 0; r < 4; ++r)
          pk[r] = (short)f2bf((acc[mi][ni][r] + bval) * scale);
        *(bf16x4*)&O[((size_t)(b * NHEAD + h) * HD + d) * SEQ + nn] = pk;
      }
    }
  }
}

// Causal flash attention, KVBLK=64, LDS-staged K/V, 3-buffer counted-vmcnt
// pipeline (one raw barrier per tile, loads stay in flight across it).
// Q pre-scaled by 0.125*log2(e). Q,K: [bh][n][64]; Vt: [bh][64][n]; all bf16.
// O: [b][n][HID] bf16. 4 waves/block over 64 q-rows of one bh.
// LDS tiles [64][64] (128 B rows), chunk ^= (row&7) XOR swizzle via
// pre-swizzled global source + swizzled reads (rule 21).
__global__ __launch_bounds__(256)
void attn_fwd(const u16* __restrict__ Q, const u16* __restrict__ K,
              const u16* __restrict__ Vt, u16* __restrict__ O)
{
  __shared__ u16 KB[3][4096];   // 24 KB
  __shared__ u16 VB[3][4096];   // 24 KB
  const int bh = blockIdx.y;
  const int t = threadIdx.x;
  const int w = t >> 6, lane = t & 63;
  const int grp = lane >> 4, lr = lane & 15;
  const int qt = gridDim.x - 1 - blockIdx.x;   // heavy blocks dispatch first
  const int q0 = qt * 64 + w * 16;
  const int nt = qt + 1;                       // causal tile count
  const size_t base = (size_t)bh * SEQ * HD;
  const float NEGINF = -__builtin_inff();

  const int srow = lane >> 3;
  const int scol = (lane & 7) ^ srow;          // pre-swizzled global source
  const u16* kg = K + base + (size_t)(w * 8 + srow) * HD + scol * 8;
  const u16* vg = Vt + base + (size_t)(w * 8 + srow) * SEQ + scol * 8;

  const bf16x8 aq0 = *(const bf16x8*)&Q[base + (size_t)(q0 + lr) * HD + grp * 8];
  const bf16x8 aq1 = *(const bf16x8*)&Q[base + (size_t)(q0 + lr) * HD + grp * 8 + 32];

  float m_i = NEGINF, l_i = 0.f;
  f32x4 o_acc[4];
#pragma unroll
  for (int c = 0; c < 4; ++c) o_acc[c] = (f32x4){0.f, 0.f, 0.f, 0.f};

  const int qg = q0 + lr;   // q row whose stats this lane owns
  const int sw = lr & 7;

#define STAGE(bi, j0)                                              \
  {                                                                \
    const u16* ks = kg + (size_t)(j0) * HD;                        \
    const u16* vs = vg + (j0);                                     \
    u16* kl = &KB[bi][w * 512];                                    \
    u16* vl = &VB[bi][w * 512];                                    \
    GLOAD_LDS16(ks, kl);                                           \
    GLOAD_LDS16(ks + (size_t)32 * HD, kl + 2048);                  \
    GLOAD_LDS16(vs, vl);                                           \
    GLOAD_LDS16(vs + (size_t)32 * SEQ, vl + 2048);                 \
  }

  STAGE(0, 0);
  if (nt > 1) STAGE(1, 64);

  for (int it = 0; it < nt; ++it) {
    const int bi = it % 3;
    if (it + 1 < nt) asm volatile("s_waitcnt vmcnt(4)" ::: "memory");
    else             asm volatile("s_waitcnt vmcnt(0)" ::: "memory");
    __builtin_amdgcn_s_barrier();
    __builtin_amdgcn_sched_barrier(0);
    asm volatile("" ::: "memory");
    if (it + 2 < nt) STAGE((it + 2) % 3, (it + 2) * 64);

    // ---- QK^T: S^T[kv][q] (swapped operands) ----
    f32x4 sv[4];
    __builtin_amdgcn_s_setprio(1);
#pragma unroll
    for (int st = 0; st < 4; ++st) {
      const int ro = (st * 16 + lr) * 64;
      bf16x8 k0 = *(const bf16x8*)&KB[bi][ro + ((grp ^ sw) * 8)];
      bf16x8 k1 = *(const bf16x8*)&KB[bi][ro + (((grp + 4) ^ sw) * 8)];
      f32x4 s = (f32x4){0.f, 0.f, 0.f, 0.f};
      s = __builtin_amdgcn_mfma_f32_16x16x32_bf16(k0, aq0, s, 0, 0, 0);
      s = __builtin_amdgcn_mfma_f32_16x16x32_bf16(k1, aq1, s, 0, 0, 0);
      sv[st] = s;
    }
    __builtin_amdgcn_s_setprio(0);

    // V B-frags (independent -> latency hides under softmax)
    bf16x4 bv[4][4];
#pragma unroll
    for (int st = 0; st < 4; ++st)
#pragma unroll
      for (int c = 0; c < 4; ++c)
        bv[st][c] = *(const bf16x4*)&VB[bi][(c * 16 + lr) * 64 +
                        (((st * 2 + (grp >> 1)) ^ sw) * 8) + (grp & 1) * 4];

    if (it == nt - 1) {  // causal mask on diagonal tile (uniform branch)
      const int j0 = it << 6;
#pragma unroll
      for (int st = 0; st < 4; ++st)
#pragma unroll
        for (int r = 0; r < 4; ++r)
          if (j0 + st * 16 + grp * 4 + r > qg) sv[st][r] = NEGINF;
    }
    // ---- online softmax over 64 kv for q = lr ----
    float tm = NEGINF;
#pragma unroll
    for (int st = 0; st < 4; ++st)
      tm = fmaxf(tm, fmaxf(fmaxf(sv[st][0], sv[st][1]), fmaxf(sv[st][2], sv[st][3])));
    tm = fmaxf(tm, __shfl_xor(tm, 16));
    tm = fmaxf(tm, __shfl_xor(tm, 32));
    // T13 defer-rescale: only rescale when the running max grows materially
    if (!__all(tm <= m_i + 8.f)) {
      const float m_new = fmaxf(m_i, tm);
      const float alpha = exp2f(m_i - m_new);  // first tile: exp2(-inf)=0
      l_i *= alpha;
      float af4[4];
#pragma unroll
      for (int r = 0; r < 4; ++r) af4[r] = __shfl(alpha, (lane & 48) + grp * 4 + r);
#pragma unroll
      for (int c = 0; c < 4; ++c)
#pragma unroll
        for (int r = 0; r < 4; ++r) o_acc[c][r] *= af4[r];
      m_i = m_new;
    }
    float rs = 0.f;
#pragma unroll
    for (int st = 0; st < 4; ++st)
#pragma unroll
      for (int r = 0; r < 4; ++r) {
        sv[st][r] = exp2f(sv[st][r] - m_i);   // bounded by 2^8 when deferred
        rs += sv[st][r];
      }
    rs += __shfl_xor(rs, 16);
    rs += __shfl_xor(rs, 32);
    l_i += rs;
    bf16x4 pa[4];
#pragma unroll
    for (int st = 0; st < 4; ++st)
#pragma unroll
      for (int r = 0; r < 4; ++r) pa[st][r] = (short)f2bf(sv[st][r]);
    // ---- PV ----
    __builtin_amdgcn_s_setprio(1);
#pragma unroll
    for (int st = 0; st < 4; ++st)
#pragma unroll
      for (int c = 0; c < 4; ++c)
        o_acc[c] = __builtin_amdgcn_mfma_f32_16x16x16bf16_1k(pa[st], bv[st][c],
                                                             o_acc[c], 0, 0, 0);
    __builtin_amdgcn_s_setprio(0);
  }
#undef STAGE

  const int b = bh >> 4, h = bh & (NHEAD - 1);
#pragma unroll
  for (int r = 0; r < 4; ++r) {
    const float li = __shfl(l_i, (lane & 48) + grp * 4 + r);
    const float inv = 1.f / li;
    const int n = q0 + grp * 4 + r;
#pragma unroll
    for (int c = 0; c < 4; ++c)
      O[(size_t)(b * SEQ + n) * HID + h * HD + c * 16 + lr] =
          f2bf(o_acc[c][r] * inv);
  }
}

extern "C" void kernel_launch(void* const* d_in, const int* in_sizes, int n_in,
                              void* d_out, int out_size, void* d_ws, size_t ws_size,
                              hipStream_t stream) {
  const float* q  = (const float*)d_in[0];
  const float* k  = (const float*)d_in[1];
  const float* v  = (const float*)d_in[2];
  /* d_in[3] = mask: tril by construction -> causal handled structurally */
  const float* Wq = (const float*)d_in[4];
  const float* bq = (const float*)d_in[5];
  const float* Wk = (const float*)d_in[6];
  const float* bk = (const float*)d_in[7];
  const float* Wv = (const float*)d_in[8];
  const float* bv = (const float*)d_in[9];
  const float* Wp = (const float*)d_in[10];
  const float* bp = (const float*)d_in[11];

  // ws layout (40 MiB): cb (conv buffer, later AO) | Wq..Wp bf16 | Qh | Kh | Vt
  char* ws = (char*)d_ws;
  u16* cb  = (u16*)(ws);                          // 8 MiB
  u16* Wqb = (u16*)(ws + ( 8u << 20));            // 2 MiB each
  u16* Wkb = (u16*)(ws + (10u << 20));
  u16* Wvb = (u16*)(ws + (12u << 20));
  u16* Wpb = (u16*)(ws + (14u << 20));
  u16* Qh  = (u16*)(ws + (16u << 20));            // 8 MiB each
  u16* Kh  = (u16*)(ws + (24u << 20));
  u16* Vt  = (u16*)(ws + (32u << 20));
  u16* AO  = cb;                                  // alias: cb free after V-gemm

  const int NV_A = MROWS * HID / 8;   // 524288 -> 2048 blocks
  const int NV_W = HID * HID / 8;     // 131072 -> 512 blocks
  const dim3 gg(HID / 128, MROWS / 64);  // (8, 64) = 512 blocks
  const float qscale = 0.125f * 1.4426950408889634f;  // 1/sqrt(64) * log2(e)

  conv_f32_bf16<<<NV_W / 256, 256, 0, stream>>>(Wq, Wqb, NV_W);
  conv_f32_bf16<<<NV_W / 256, 256, 0, stream>>>(Wk, Wkb, NV_W);
  conv_f32_bf16<<<NV_W / 256, 256, 0, stream>>>(Wv, Wvb, NV_W);
  conv_f32_bf16<<<NV_W / 256, 256, 0, stream>>>(Wp, Wpb, NV_W);

  conv_f32_bf16<<<NV_A / 256, 256, 0, stream>>>(q, cb, NV_A);
  gemm_bf16<<<gg, 256, 0, stream>>>(cb, Wqb, bq, Qh, qscale, 0);
  conv_f32_bf16<<<NV_A / 256, 256, 0, stream>>>(k, cb, NV_A);
  gemm_bf16<<<gg, 256, 0, stream>>>(cb, Wkb, bk, Kh, 1.0f, 0);
  conv_f32_bf16<<<NV_A / 256, 256, 0, stream>>>(v, cb, NV_A);
  gemm_bf16<<<gg, 256, 0, stream>>>(cb, Wvb, bv, Vt, 1.0f, 2);

  attn_fwd<<<dim3(SEQ / 64, NB * NHEAD), 256, 0, stream>>>(Qh, Kh, Vt, AO);

  gemm_bf16<<<gg, 256, 0, stream>>>(AO, Wpb, bp, d_out, 1.0f, 1);
}

// Round 6
// 176.482 us; speedup vs baseline: 1.2792x; 1.2792x over previous
//
#include <hip/hip_runtime.h>

typedef unsigned short u16;
typedef __attribute__((ext_vector_type(8))) short bf16x8;
typedef __attribute__((ext_vector_type(4))) short bf16x4;
typedef __attribute__((ext_vector_type(4))) float f32x4;

#define NB 2
#define SEQ 2048
#define HID 1024
#define NHEAD 16
#define HD 64
#define MROWS (NB * SEQ) /* 4096 */

__device__ __forceinline__ u16 f2bf(float f) {
  union { float f; unsigned u; } x; x.f = f;
  unsigned r = x.u + 0x7fffu + ((x.u >> 16) & 1u);
  return (u16)(r >> 16);
}
__device__ __forceinline__ u16 f2bf_trunc(float f) {
  union { float f; unsigned u; } x; x.f = f;
  return (u16)(x.u >> 16);
}

#define GLOAD_LDS16(g, l)                                                   \
  __builtin_amdgcn_global_load_lds(                                         \
      (const __attribute__((address_space(1))) void*)(g),                   \
      (__attribute__((address_space(3))) void*)(l), 16, 0, 0)

// single-tensor f32 -> bf16 (fallback path)
__global__ __launch_bounds__(256)
void conv_f32_bf16(const float* __restrict__ src, u16* __restrict__ dst, int nvec)
{
  const int i = blockIdx.x * 256 + threadIdx.x;
  if (i >= nvec) return;
  const float* s = src + (size_t)i * 8;
  f32x4 a = *(const f32x4*)s;
  f32x4 b = *(const f32x4*)(s + 4);
  bf16x8 o;
#pragma unroll
  for (int j = 0; j < 4; ++j) { o[j] = (short)f2bf(a[j]); o[4 + j] = (short)f2bf(b[j]); }
  *(bf16x8*)(dst + (size_t)i * 8) = o;
}

// all-tensor f32 -> bf16: q,k,v (4M elems each) + Wq,Wk,Wv -> Wcat + Wp -> Wpb
__global__ __launch_bounds__(256)
void conv_all(const float* __restrict__ q, const float* __restrict__ k,
              const float* __restrict__ v, const float* __restrict__ wq,
              const float* __restrict__ wk, const float* __restrict__ wv,
              const float* __restrict__ wp, u16* __restrict__ qb,
              u16* __restrict__ kb, u16* __restrict__ vb,
              u16* __restrict__ wcat, u16* __restrict__ wpb)
{
  const int i = blockIdx.x * 256 + threadIdx.x;  // vec8 index, < 2097152
  const float* s; u16* d;
  if (i < 1572864) {
    const int seg = i / 524288;          // 0=q 1=k 2=v
    const int off = i - seg * 524288;
    s = (seg == 0 ? q : seg == 1 ? k : v) + (size_t)off * 8;
    d = (seg == 0 ? qb : seg == 1 ? kb : vb) + (size_t)off * 8;
  } else {
    const int j = i - 1572864;
    const int seg = j / 131072;          // 0=Wq 1=Wk 2=Wv 3=Wp
    const int off = j - seg * 131072;
    s = (seg == 0 ? wq : seg == 1 ? wk : seg == 2 ? wv : wp) + (size_t)off * 8;
    d = (seg < 3 ? wcat + (size_t)seg * 1048576 : wpb) + (size_t)off * 8;
  }
  f32x4 a = *(const f32x4*)s;
  f32x4 b = *(const f32x4*)(s + 4);
  bf16x8 o;
#pragma unroll
  for (int j = 0; j < 4; ++j) { o[j] = (short)f2bf(a[j]); o[4 + j] = (short)f2bf(b[j]); }
  *(bf16x8*)d = o;
}

// 128x128x32 m97-structure GEMM.  C = (A @ W.T + bias) * scale.
// MODE 0 (QKV): column group g = n0>>10 selects A/bias/epilogue:
//   wm==0 -> Qh split-head bf16 (scaled), wm==1 -> Kh split-head,
//   wm==2 -> Vt transposed [b][h][d][n].
// MODE 1: f32 row-major Op.
// wparam: -1 = derive wm from g (fused); else fixed wm (separate launches).
template<int MODE>
__global__ __launch_bounds__(256)
void gemm128(const u16* __restrict__ A0, const u16* __restrict__ A1,
             const u16* __restrict__ A2, const u16* __restrict__ W,
             const float* __restrict__ b0, const float* __restrict__ b1,
             const float* __restrict__ b2,
             u16* __restrict__ Qh, u16* __restrict__ Kh, u16* __restrict__ Vt,
             float* __restrict__ Op, int wparam, float qscale)
{
  __shared__ u16 As[128 * 32];   // 8 KB, linear
  __shared__ u16 Bs[128 * 32];   // 8 KB
  const int n0 = blockIdx.x * 128, m0 = blockIdx.y * 128;
  const int g = n0 >> 10;
  const int wm = wparam < 0 ? g : wparam;
  const u16* A = (g == 0) ? A0 : (g == 1) ? A1 : A2;
  const float* bias = (wm == 0) ? b0 : (wm == 1) ? b1 : b2;
  const float scale = (MODE == 0 && wm == 0) ? qscale : 1.f;
  const int t = threadIdx.x, lane = t & 63, w = t >> 6;
  const int grp = lane >> 4, lr = lane & 15;
  const int wr = (w >> 1) * 64, wc = (w & 1) * 64;

  f32x4 acc[4][4];
#pragma unroll
  for (int i = 0; i < 4; ++i)
#pragma unroll
    for (int j = 0; j < 4; ++j) acc[i][j] = (f32x4){0.f, 0.f, 0.f, 0.f};

  // staging: wave w covers rows [w*32, w*32+32); lane l -> row +l/4, col (l&3)*8
  const int sr = lane >> 2, sc = (lane & 3) * 8;
  const u16* ag = A + (size_t)(m0 + w * 32 + sr) * HID + sc;
  const u16* wg = W + (size_t)(n0 + w * 32 + sr) * HID + sc;
  u16* al = As + (w * 32) * 32;
  u16* bl = Bs + (w * 32) * 32;

  for (int k0 = 0; k0 < HID; k0 += 32) {
    GLOAD_LDS16(ag + k0, al);
    GLOAD_LDS16(ag + (size_t)16 * HID + k0, al + 16 * 32);
    GLOAD_LDS16(wg + k0, bl);
    GLOAD_LDS16(wg + (size_t)16 * HID + k0, bl + 16 * 32);
    __syncthreads();
    bf16x8 af[4], bf[4];
#pragma unroll
    for (int mi = 0; mi < 4; ++mi)
      af[mi] = *(const bf16x8*)&As[(wr + mi * 16 + lr) * 32 + grp * 8];
#pragma unroll
    for (int ni = 0; ni < 4; ++ni)
      bf[ni] = *(const bf16x8*)&Bs[(wc + ni * 16 + lr) * 32 + grp * 8];
    __builtin_amdgcn_s_setprio(1);
#pragma unroll
    for (int mi = 0; mi < 4; ++mi)
#pragma unroll
      for (int ni = 0; ni < 4; ++ni)
        acc[mi][ni] = __builtin_amdgcn_mfma_f32_16x16x32_bf16(
            af[mi], bf[ni], acc[mi][ni], 0, 0, 0);
    __builtin_amdgcn_s_setprio(0);
    __syncthreads();
  }

#pragma unroll
  for (int mi = 0; mi < 4; ++mi) {
#pragma unroll
    for (int ni = 0; ni < 4; ++ni) {
      const int n = n0 + wc + ni * 16 + lr;
      const int nl = n & (HID - 1);
      const float bval = bias[nl];
      const int mb = m0 + wr + mi * 16 + grp * 4;
      if (MODE == 1) {
#pragma unroll
        for (int r = 0; r < 4; ++r)
          Op[(size_t)(mb + r) * HID + n] = acc[mi][ni][r] + bval;
      } else {
        const int h = nl >> 6, d = nl & (HD - 1);
        if (wm == 2) {  // V transposed: vector over r (m-contiguous)
          const int b = mb >> 11, nn = mb & (SEQ - 1);
          bf16x4 pk;
#pragma unroll
          for (int r = 0; r < 4; ++r)
            pk[r] = (short)f2bf(acc[mi][ni][r] + bval);
          *(bf16x4*)&Vt[((size_t)(b * NHEAD + h) * HD + d) * SEQ + nn] = pk;
        } else {
          u16* O = (wm == 0) ? Qh : Kh;
#pragma unroll
          for (int r = 0; r < 4; ++r) {
            const int m = mb + r;
            const int b = m >> 11, nn = m & (SEQ - 1);
            O[((size_t)(b * NHEAD + h) * SEQ + nn) * HD + d] =
                f2bf((acc[mi][ni][r] + bval) * scale);
          }
        }
      }
    }
  }
}

// Causal flash attention. QBLK=128 (8 waves x 16 q-rows), KVBLK=64,
// 2-buffer LDS (32 KB), 1-deep prefetch, one raw barrier per tile.
// Q pre-scaled by 0.125*log2(e). Q,K: [bh][n][64]; Vt: [bh][64][n]; bf16.
// O: [b][n][HID] bf16. chunk ^= (row&7) XOR swizzle (pre-swizzled source).
__global__ __launch_bounds__(512)
void attn_fwd(const u16* __restrict__ Q, const u16* __restrict__ K,
              const u16* __restrict__ Vt, u16* __restrict__ O)
{
  __shared__ u16 KB[2][4096];   // [buf][64 kv][64 d], 8 KB each
  __shared__ u16 VB[2][4096];   // [buf][64 d][64 kv], 8 KB each
  const int bh = blockIdx.y;
  const int t = threadIdx.x;
  const int w = t >> 6, lane = t & 63;
  const int grp = lane >> 4, lr = lane & 15;
  const int qt = gridDim.x - 1 - blockIdx.x;   // heavy blocks dispatch first
  const int q0 = qt * 128 + w * 16;
  const int nt = 2 * qt + 2;                   // kv tiles for this block
  const size_t base = (size_t)bh * SEQ * HD;
  const float NEGINF = -__builtin_inff();

  // staging: wave w covers tile rows [w*8, w*8+8); chunk pre-swizzled
  const int srow = lane >> 3;
  const int scol = (lane & 7) ^ srow;
  const u16* kg = K + base + (size_t)(w * 8 + srow) * HD + scol * 8;
  const u16* vg = Vt + base + (size_t)(w * 8 + srow) * SEQ + scol * 8;

  const bf16x8 aq0 = *(const bf16x8*)&Q[base + (size_t)(q0 + lr) * HD + grp * 8];
  const bf16x8 aq1 = *(const bf16x8*)&Q[base + (size_t)(q0 + lr) * HD + grp * 8 + 32];

  float m_i = NEGINF, l_i = 0.f;
  f32x4 o_acc[4];
#pragma unroll
  for (int c = 0; c < 4; ++c) o_acc[c] = (f32x4){0.f, 0.f, 0.f, 0.f};

  const int qg = q0 + lr;     // q row whose stats this lane owns
  const int idq = q0 >> 6;    // this wave's diagonal tile; beyond it: dead
  const int sw = lr & 7;

#define STAGE(bi, j0)                                              \
  {                                                                \
    GLOAD_LDS16(kg + (size_t)(j0) * HD, &KB[bi][w * 512]);         \
    GLOAD_LDS16(vg + (j0), &VB[bi][w * 512]);                      \
  }

  STAGE(0, 0);

  for (int it = 0; it < nt; ++it) {
    const int bi = it & 1;
    asm volatile("s_waitcnt vmcnt(0)" ::: "memory");
    __builtin_amdgcn_s_barrier();
    __builtin_amdgcn_sched_barrier(0);
    asm volatile("" ::: "memory");
    if (it + 1 < nt) STAGE(bi ^ 1, (it + 1) << 6);

    if (it <= idq) {   // wave-uniform: skip fully-masked tiles
      // ---- QK^T: S^T[kv][q] (swapped operands) ----
      f32x4 sv[4];
      __builtin_amdgcn_s_setprio(1);
#pragma unroll
      for (int st = 0; st < 4; ++st) {
        const int ro = (st * 16 + lr) * 64;
        bf16x8 k0 = *(const bf16x8*)&KB[bi][ro + ((grp ^ sw) * 8)];
        bf16x8 k1 = *(const bf16x8*)&KB[bi][ro + (((grp + 4) ^ sw) * 8)];
        f32x4 s = (f32x4){0.f, 0.f, 0.f, 0.f};
        s = __builtin_amdgcn_mfma_f32_16x16x32_bf16(k0, aq0, s, 0, 0, 0);
        s = __builtin_amdgcn_mfma_f32_16x16x32_bf16(k1, aq1, s, 0, 0, 0);
        sv[st] = s;
      }
      __builtin_amdgcn_s_setprio(0);

      // V B-frags (independent -> latency hides under softmax)
      bf16x4 bv[4][4];
#pragma unroll
      for (int st = 0; st < 4; ++st)
#pragma unroll
        for (int c = 0; c < 4; ++c)
          bv[st][c] = *(const bf16x4*)&VB[bi][(c * 16 + lr) * 64 +
                          (((st * 2 + (grp >> 1)) ^ sw) * 8) + (grp & 1) * 4];

      if (it == idq) {  // causal mask on this wave's diagonal tile
        const int j0 = it << 6;
#pragma unroll
        for (int st = 0; st < 4; ++st)
#pragma unroll
          for (int r = 0; r < 4; ++r)
            if (j0 + st * 16 + grp * 4 + r > qg) sv[st][r] = NEGINF;
      }
      // ---- online softmax over 64 kv for q = lr ----
      float tm = NEGINF;
#pragma unroll
      for (int st = 0; st < 4; ++st)
        tm = fmaxf(tm, fmaxf(fmaxf(sv[st][0], sv[st][1]), fmaxf(sv[st][2], sv[st][3])));
      tm = fmaxf(tm, __shfl_xor(tm, 16));
      tm = fmaxf(tm, __shfl_xor(tm, 32));
      if (!__all(tm <= m_i + 8.f)) {  // T13 defer-rescale
        const float m_new = fmaxf(m_i, tm);
        const float alpha = exp2f(m_i - m_new);  // first tile: exp2(-inf)=0
        l_i *= alpha;
        float af4[4];
#pragma unroll
        for (int r = 0; r < 4; ++r)
          af4[r] = __shfl(alpha, (lane & 48) + grp * 4 + r);
#pragma unroll
        for (int c = 0; c < 4; ++c)
#pragma unroll
          for (int r = 0; r < 4; ++r) o_acc[c][r] *= af4[r];
        m_i = m_new;
      }
      float rs = 0.f;
#pragma unroll
      for (int st = 0; st < 4; ++st)
#pragma unroll
        for (int r = 0; r < 4; ++r) {
          sv[st][r] = exp2f(sv[st][r] - m_i);   // bounded by 2^8 when deferred
          rs += sv[st][r];
        }
      rs += __shfl_xor(rs, 16);
      rs += __shfl_xor(rs, 32);
      l_i += rs;
      bf16x4 pa[4];
#pragma unroll
      for (int st = 0; st < 4; ++st)
#pragma unroll
        for (int r = 0; r < 4; ++r) pa[st][r] = (short)f2bf_trunc(sv[st][r]);
      // ---- PV ----
      __builtin_amdgcn_s_setprio(1);
#pragma unroll
      for (int st = 0; st < 4; ++st)
#pragma unroll
        for (int c = 0; c < 4; ++c)
          o_acc[c] = __builtin_amdgcn_mfma_f32_16x16x16bf16_1k(pa[st], bv[st][c],
                                                               o_acc[c], 0, 0, 0);
      __builtin_amdgcn_s_setprio(0);
    }
  }
#undef STAGE

  const int b = bh >> 4, h = bh & (NHEAD - 1);
#pragma unroll
  for (int r = 0; r < 4; ++r) {
    const float li = __shfl(l_i, (lane & 48) + grp * 4 + r);
    const float inv = 1.f / li;
    const int n = q0 + grp * 4 + r;
#pragma unroll
    for (int c = 0; c < 4; ++c)
      O[(size_t)(b * SEQ + n) * HID + h * HD + c * 16 + lr] =
          f2bf(o_acc[c][r] * inv);
  }
}

extern "C" void kernel_launch(void* const* d_in, const int* in_sizes, int n_in,
                              void* d_out, int out_size, void* d_ws, size_t ws_size,
                              hipStream_t stream) {
  const float* q  = (const float*)d_in[0];
  const float* k  = (const float*)d_in[1];
  const float* v  = (const float*)d_in[2];
  /* d_in[3] = mask: tril by construction -> causal handled structurally */
  const float* Wq = (const float*)d_in[4];
  const float* bq = (const float*)d_in[5];
  const float* Wk = (const float*)d_in[6];
  const float* bk = (const float*)d_in[7];
  const float* Wv = (const float*)d_in[8];
  const float* bv = (const float*)d_in[9];
  const float* Wp = (const float*)d_in[10];
  const float* bp = (const float*)d_in[11];
  float* out = (float*)d_out;

  char* ws = (char*)d_ws;
  const float qscale = 0.125f * 1.4426950408889634f;  // 1/sqrt(64) * log2(e)
  const dim3 ablk(SEQ / 128, NB * NHEAD);             // (16, 32)

  if (ws_size >= (56u << 20)) {
    // fused path (56 MiB): qb kb vb | Wcat(3x) Wpb | Qh Kh Vt ; AO aliases qb
    u16* qb   = (u16*)(ws);
    u16* kb   = (u16*)(ws + ( 8u << 20));
    u16* vb   = (u16*)(ws + (16u << 20));
    u16* Wcat = (u16*)(ws + (24u << 20));
    u16* Wpb  = (u16*)(ws + (30u << 20));
    u16* Qh   = (u16*)(ws + (32u << 20));
    u16* Kh   = (u16*)(ws + (40u << 20));
    u16* Vt   = (u16*)(ws + (48u << 20));
    u16* AO   = qb;

    conv_all<<<8192, 256, 0, stream>>>(q, k, v, Wq, Wk, Wv, Wp,
                                       qb, kb, vb, Wcat, Wpb);
    gemm128<0><<<dim3(24, 32), 256, 0, stream>>>(
        qb, kb, vb, Wcat, bq, bk, bv, Qh, Kh, Vt, nullptr, -1, qscale);
    attn_fwd<<<ablk, 512, 0, stream>>>(Qh, Kh, Vt, AO);
    gemm128<1><<<dim3(8, 32), 256, 0, stream>>>(
        AO, AO, AO, Wpb, bp, bp, bp, nullptr, nullptr, nullptr, out, 0, 1.f);
  } else {
    // fallback (40 MiB): cb | Wqb Wkb Wvb Wpb | Qh Kh Vt ; AO aliases cb
    u16* cb  = (u16*)(ws);
    u16* Wqb = (u16*)(ws + ( 8u << 20));
    u16* Wkb = (u16*)(ws + (10u << 20));
    u16* Wvb = (u16*)(ws + (12u << 20));
    u16* Wpb = (u16*)(ws + (14u << 20));
    u16* Qh  = (u16*)(ws + (16u << 20));
    u16* Kh  = (u16*)(ws + (24u << 20));
    u16* Vt  = (u16*)(ws + (32u << 20));
    u16* AO  = cb;
    const int NV_A = MROWS * HID / 8, NV_W = HID * HID / 8;

    conv_f32_bf16<<<NV_W / 256, 256, 0, stream>>>(Wq, Wqb, NV_W);
    conv_f32_bf16<<<NV_W / 256, 256, 0, stream>>>(Wk, Wkb, NV_W);
    conv_f32_bf16<<<NV_W / 256, 256, 0, stream>>>(Wv, Wvb, NV_W);
    conv_f32_bf16<<<NV_W / 256, 256, 0, stream>>>(Wp, Wpb, NV_W);

    conv_f32_bf16<<<NV_A / 256, 256, 0, stream>>>(q, cb, NV_A);
    gemm128<0><<<dim3(8, 32), 256, 0, stream>>>(
        cb, cb, cb, Wqb, bq, bk, bv, Qh, Kh, Vt, nullptr, 0, qscale);
    conv_f32_bf16<<<NV_A / 256, 256, 0, stream>>>(k, cb, NV_A);
    gemm128<0><<<dim3(8, 32), 256, 0, stream>>>(
        cb, cb, cb, Wkb, bq, bk, bv, Qh, Kh, Vt, nullptr, 1, qscale);
    conv_f32_bf16<<<NV_A / 256, 256, 0, stream>>>(v, cb, NV_A);
    gemm128<0><<<dim3(8, 32), 256, 0, stream>>>(
        cb, cb, cb, Wvb, bq, bk, bv, Qh, Kh, Vt, nullptr, 2, qscale);

    attn_fwd<<<ablk, 512, 0, stream>>>(Qh, Kh, Vt, AO);
    gemm128<1><<<dim3(8, 32), 256, 0, stream>>>(
        AO, AO, AO, Wpb, bp, bp, bp, nullptr, nullptr, nullptr, out, 0, 1.f);
  }
}

// Round 7
// 162.668 us; speedup vs baseline: 1.3878x; 1.0849x over previous
//
#include <hip/hip_runtime.h>

typedef unsigned short u16;
typedef __attribute__((ext_vector_type(8))) short bf16x8;
typedef __attribute__((ext_vector_type(4))) short bf16x4;
typedef __attribute__((ext_vector_type(4))) float f32x4;

#define NB 2
#define SEQ 2048
#define HID 1024
#define NHEAD 16
#define HD 64
#define MROWS (NB * SEQ) /* 4096 */

__device__ __forceinline__ u16 f2bf(float f) {
  union { float f; unsigned u; } x; x.f = f;
  unsigned r = x.u + 0x7fffu + ((x.u >> 16) & 1u);
  return (u16)(r >> 16);
}
__device__ __forceinline__ u16 f2bf_trunc(float f) {
  union { float f; unsigned u; } x; x.f = f;
  return (u16)(x.u >> 16);
}

#define GLOAD_LDS16(g, l)                                                   \
  __builtin_amdgcn_global_load_lds(                                         \
      (const __attribute__((address_space(1))) void*)(g),                   \
      (__attribute__((address_space(3))) void*)(l), 16, 0, 0)

// single-tensor f32 -> bf16 (fallback path)
__global__ __launch_bounds__(256)
void conv_f32_bf16(const float* __restrict__ src, u16* __restrict__ dst, int nvec)
{
  const int i = blockIdx.x * 256 + threadIdx.x;
  if (i >= nvec) return;
  const float* s = src + (size_t)i * 8;
  f32x4 a = *(const f32x4*)s;
  f32x4 b = *(const f32x4*)(s + 4);
  bf16x8 o;
#pragma unroll
  for (int j = 0; j < 4; ++j) { o[j] = (short)f2bf(a[j]); o[4 + j] = (short)f2bf(b[j]); }
  *(bf16x8*)(dst + (size_t)i * 8) = o;
}

// all-tensor f32 -> bf16: q,k,v (4M elems each) + Wq,Wk,Wv -> Wcat + Wp -> Wpb
__global__ __launch_bounds__(256)
void conv_all(const float* __restrict__ q, const float* __restrict__ k,
              const float* __restrict__ v, const float* __restrict__ wq,
              const float* __restrict__ wk, const float* __restrict__ wv,
              const float* __restrict__ wp, u16* __restrict__ qb,
              u16* __restrict__ kb, u16* __restrict__ vb,
              u16* __restrict__ wcat, u16* __restrict__ wpb)
{
  const int i = blockIdx.x * 256 + threadIdx.x;  // vec8 index, < 2097152
  const float* s; u16* d;
  if (i < 1572864) {
    const int seg = i / 524288;          // 0=q 1=k 2=v
    const int off = i - seg * 524288;
    s = (seg == 0 ? q : seg == 1 ? k : v) + (size_t)off * 8;
    d = (seg == 0 ? qb : seg == 1 ? kb : vb) + (size_t)off * 8;
  } else {
    const int j = i - 1572864;
    const int seg = j / 131072;          // 0=Wq 1=Wk 2=Wv 3=Wp
    const int off = j - seg * 131072;
    s = (seg == 0 ? wq : seg == 1 ? wk : seg == 2 ? wv : wp) + (size_t)off * 8;
    d = (seg < 3 ? wcat + (size_t)seg * 1048576 : wpb) + (size_t)off * 8;
  }
  f32x4 a = *(const f32x4*)s;
  f32x4 b = *(const f32x4*)(s + 4);
  bf16x8 o;
#pragma unroll
  for (int j = 0; j < 4; ++j) { o[j] = (short)f2bf(a[j]); o[4 + j] = (short)f2bf(b[j]); }
  *(bf16x8*)d = o;
}

// 128x128x32 m97-structure GEMM.  C = (A @ W.T + bias) * scale.
// MODE 0 (QKV): column group g = n0>>10 selects A/bias/epilogue:
//   wm==0 -> Qh split-head bf16 (scaled), wm==1 -> Kh split-head,
//   wm==2 -> Vt transposed [b][h][d][n].
// MODE 1: f32 row-major Op.
// wparam: -1 = derive wm from g (fused); else fixed wm (separate launches).
template<int MODE>
__global__ __launch_bounds__(256)
void gemm128(const u16* __restrict__ A0, const u16* __restrict__ A1,
             const u16* __restrict__ A2, const u16* __restrict__ W,
             const float* __restrict__ b0, const float* __restrict__ b1,
             const float* __restrict__ b2,
             u16* __restrict__ Qh, u16* __restrict__ Kh, u16* __restrict__ Vt,
             float* __restrict__ Op, int wparam, float qscale)
{
  __shared__ u16 As[128 * 32];   // 8 KB, linear
  __shared__ u16 Bs[128 * 32];   // 8 KB
  const int n0 = blockIdx.x * 128, m0 = blockIdx.y * 128;
  const int g = n0 >> 10;
  const int wm = wparam < 0 ? g : wparam;
  const u16* A = (g == 0) ? A0 : (g == 1) ? A1 : A2;
  const float* bias = (wm == 0) ? b0 : (wm == 1) ? b1 : b2;
  const float scale = (MODE == 0 && wm == 0) ? qscale : 1.f;
  const int t = threadIdx.x, lane = t & 63, w = t >> 6;
  const int grp = lane >> 4, lr = lane & 15;
  const int wr = (w >> 1) * 64, wc = (w & 1) * 64;

  f32x4 acc[4][4];
#pragma unroll
  for (int i = 0; i < 4; ++i)
#pragma unroll
    for (int j = 0; j < 4; ++j) acc[i][j] = (f32x4){0.f, 0.f, 0.f, 0.f};

  // staging: wave w covers rows [w*32, w*32+32); lane l -> row +l/4, col (l&3)*8
  const int sr = lane >> 2, sc = (lane & 3) * 8;
  const u16* ag = A + (size_t)(m0 + w * 32 + sr) * HID + sc;
  const u16* wg = W + (size_t)(n0 + w * 32 + sr) * HID + sc;
  u16* al = As + (w * 32) * 32;
  u16* bl = Bs + (w * 32) * 32;

  for (int k0 = 0; k0 < HID; k0 += 32) {
    GLOAD_LDS16(ag + k0, al);
    GLOAD_LDS16(ag + (size_t)16 * HID + k0, al + 16 * 32);
    GLOAD_LDS16(wg + k0, bl);
    GLOAD_LDS16(wg + (size_t)16 * HID + k0, bl + 16 * 32);
    __syncthreads();
    bf16x8 af[4], bf[4];
#pragma unroll
    for (int mi = 0; mi < 4; ++mi)
      af[mi] = *(const bf16x8*)&As[(wr + mi * 16 + lr) * 32 + grp * 8];
#pragma unroll
    for (int ni = 0; ni < 4; ++ni)
      bf[ni] = *(const bf16x8*)&Bs[(wc + ni * 16 + lr) * 32 + grp * 8];
    __builtin_amdgcn_s_setprio(1);
#pragma unroll
    for (int mi = 0; mi < 4; ++mi)
#pragma unroll
      for (int ni = 0; ni < 4; ++ni)
        acc[mi][ni] = __builtin_amdgcn_mfma_f32_16x16x32_bf16(
            af[mi], bf[ni], acc[mi][ni], 0, 0, 0);
    __builtin_amdgcn_s_setprio(0);
    __syncthreads();
  }

#pragma unroll
  for (int mi = 0; mi < 4; ++mi) {
#pragma unroll
    for (int ni = 0; ni < 4; ++ni) {
      const int n = n0 + wc + ni * 16 + lr;
      const int nl = n & (HID - 1);
      const float bval = bias[nl];
      const int mb = m0 + wr + mi * 16 + grp * 4;
      if (MODE == 1) {
#pragma unroll
        for (int r = 0; r < 4; ++r)
          Op[(size_t)(mb + r) * HID + n] = acc[mi][ni][r] + bval;
      } else {
        const int h = nl >> 6, d = nl & (HD - 1);
        if (wm == 2) {  // V transposed: vector over r (m-contiguous)
          const int b = mb >> 11, nn = mb & (SEQ - 1);
          bf16x4 pk;
#pragma unroll
          for (int r = 0; r < 4; ++r)
            pk[r] = (short)f2bf(acc[mi][ni][r] + bval);
          *(bf16x4*)&Vt[((size_t)(b * NHEAD + h) * HD + d) * SEQ + nn] = pk;
        } else {
          u16* O = (wm == 0) ? Qh : Kh;
#pragma unroll
          for (int r = 0; r < 4; ++r) {
            const int m = mb + r;
            const int b = m >> 11, nn = m & (SEQ - 1);
            O[((size_t)(b * NHEAD + h) * SEQ + nn) * HD + d] =
                f2bf((acc[mi][ni][r] + bval) * scale);
          }
        }
      }
    }
  }
}

// Causal flash attention with PAIRED q-tiles: block (qtA, qtB=15-qtA) of one
// bh. B's kv range is a superset of A's, so each staged K/V tile feeds both
// q-tiles' compute (shared staging, balanced 36 computes/block, grid 256 =
// 1 block/CU, no tail). QBLK=128 (8 waves x 16 q-rows), KVBLK=64, 2-buffer
// LDS, one raw barrier per staged tile. Q pre-scaled by 0.125*log2(e).
// Q,K: [bh][n][64]; Vt: [bh][64][n]; bf16. O: [b][n][HID] bf16.
// chunk ^= (row&7) XOR swizzle via pre-swizzled global source (rule 21).
__global__ __launch_bounds__(512)
void attn_fwd(const u16* __restrict__ Q, const u16* __restrict__ K,
              const u16* __restrict__ Vt, u16* __restrict__ O)
{
  __shared__ u16 KB[2][4096];   // [buf][64 kv][64 d], 8 KB each
  __shared__ u16 VB[2][4096];   // [buf][64 d][64 kv], 8 KB each
  const int bh = blockIdx.y;
  const int t = threadIdx.x;
  const int w = t >> 6, lane = t & 63;
  const int grp = lane >> 4, lr = lane & 15;
  const int qtA = blockIdx.x;          // 0..7  (light tile)
  const int qtB = 15 - qtA;            // 8..15 (heavy tile)
  const int q0A = qtA * 128 + w * 16;
  const int q0B = qtB * 128 + w * 16;
  const int ntB = 2 * qtB + 2;         // staged kv tiles (covers A too)
  const size_t base = (size_t)bh * SEQ * HD;
  const float NEGINF = -__builtin_inff();

  // staging: wave w covers tile rows [w*8, w*8+8); chunk pre-swizzled
  const int srow = lane >> 3;
  const int scol = (lane & 7) ^ srow;
  const u16* kg = K + base + (size_t)(w * 8 + srow) * HD + scol * 8;
  const u16* vg = Vt + base + (size_t)(w * 8 + srow) * SEQ + scol * 8;

  const bf16x8 aqA0 = *(const bf16x8*)&Q[base + (size_t)(q0A + lr) * HD + grp * 8];
  const bf16x8 aqA1 = *(const bf16x8*)&Q[base + (size_t)(q0A + lr) * HD + grp * 8 + 32];
  const bf16x8 aqB0 = *(const bf16x8*)&Q[base + (size_t)(q0B + lr) * HD + grp * 8];
  const bf16x8 aqB1 = *(const bf16x8*)&Q[base + (size_t)(q0B + lr) * HD + grp * 8 + 32];

  float mA = NEGINF, lA = 0.f, mB = NEGINF, lB = 0.f;
  f32x4 oA[4], oB[4];
#pragma unroll
  for (int c = 0; c < 4; ++c) {
    oA[c] = (f32x4){0.f, 0.f, 0.f, 0.f};
    oB[c] = (f32x4){0.f, 0.f, 0.f, 0.f};
  }

  const int idqA = q0A >> 6;   // this wave's diagonal tile in stream A
  const int idqB = q0B >> 6;
  const int sw = lr & 7;

#define STAGE(bi, j0)                                              \
  {                                                                \
    GLOAD_LDS16(kg + (size_t)(j0) * HD, &KB[bi][w * 512]);         \
    GLOAD_LDS16(vg + (j0), &VB[bi][w * 512]);                      \
  }

// one 64-kv tile of online-softmax attention for stream X
#define COMPUTE(Q0, AQ0, AQ1, OACC, MI, LI, IDQ)                              \
  do {                                                                        \
    f32x4 sv[4];                                                              \
    __builtin_amdgcn_s_setprio(1);                                            \
    _Pragma("unroll")                                                         \
    for (int st = 0; st < 4; ++st) {                                          \
      const int ro = (st * 16 + lr) * 64;                                     \
      bf16x8 k0 = *(const bf16x8*)&KB[bi][ro + ((grp ^ sw) * 8)];             \
      bf16x8 k1 = *(const bf16x8*)&KB[bi][ro + (((grp + 4) ^ sw) * 8)];       \
      f32x4 s = (f32x4){0.f, 0.f, 0.f, 0.f};                                  \
      s = __builtin_amdgcn_mfma_f32_16x16x32_bf16(k0, (AQ0), s, 0, 0, 0);     \
      s = __builtin_amdgcn_mfma_f32_16x16x32_bf16(k1, (AQ1), s, 0, 0, 0);     \
      sv[st] = s;                                                             \
    }                                                                         \
    __builtin_amdgcn_s_setprio(0);                                            \
    bf16x4 bv[4][4];                                                          \
    _Pragma("unroll")                                                         \
    for (int st = 0; st < 4; ++st)                                            \
      _Pragma("unroll")                                                       \
      for (int c = 0; c < 4; ++c)                                             \
        bv[st][c] = *(const bf16x4*)&VB[bi][(c * 16 + lr) * 64 +              \
                        (((st * 2 + (grp >> 1)) ^ sw) * 8) + (grp & 1) * 4];  \
    if (it == (IDQ)) {                                                        \
      const int j0 = it << 6, qg = (Q0) + lr;                                 \
      _Pragma("unroll")                                                       \
      for (int st = 0; st < 4; ++st)                                          \
        _Pragma("unroll")                                                     \
        for (int r = 0; r < 4; ++r)                                           \
          if (j0 + st * 16 + grp * 4 + r > qg) sv[st][r] = NEGINF;            \
    }                                                                         \
    float tm = NEGINF;                                                        \
    _Pragma("unroll")                                                         \
    for (int st = 0; st < 4; ++st)                                            \
      tm = fmaxf(tm, fmaxf(fmaxf(sv[st][0], sv[st][1]),                       \
                           fmaxf(sv[st][2], sv[st][3])));                     \
    tm = fmaxf(tm, __shfl_xor(tm, 16));                                       \
    tm = fmaxf(tm, __shfl_xor(tm, 32));                                       \
    if (!__all(tm <= (MI) + 8.f)) {                                           \
      const float m_new = fmaxf((MI), tm);                                    \
      const float alpha = exp2f((MI)-m_new);                                  \
      (LI) *= alpha;                                                          \
      float af4[4];                                                           \
      _Pragma("unroll")                                                       \
      for (int r = 0; r < 4; ++r)                                             \
        af4[r] = __shfl(alpha, (lane & 48) + grp * 4 + r);                    \
      _Pragma("unroll")                                                       \
      for (int c = 0; c < 4; ++c)                                             \
        _Pragma("unroll")                                                     \
        for (int r = 0; r < 4; ++r) (OACC)[c][r] *= af4[r];                   \
      (MI) = m_new;                                                           \
    }                                                                         \
    float rs = 0.f;                                                           \
    _Pragma("unroll")                                                         \
    for (int st = 0; st < 4; ++st)                                            \
      _Pragma("unroll")                                                       \
      for (int r = 0; r < 4; ++r) {                                           \
        sv[st][r] = exp2f(sv[st][r] - (MI));                                  \
        rs += sv[st][r];                                                      \
      }                                                                       \
    rs += __shfl_xor(rs, 16);                                                 \
    rs += __shfl_xor(rs, 32);                                                 \
    (LI) += rs;                                                               \
    bf16x4 pa[4];                                                             \
    _Pragma("unroll")                                                         \
    for (int st = 0; st < 4; ++st)                                            \
      _Pragma("unroll")                                                       \
      for (int r = 0; r < 4; ++r) pa[st][r] = (short)f2bf_trunc(sv[st][r]);   \
    __builtin_amdgcn_s_setprio(1);                                            \
    _Pragma("unroll")                                                         \
    for (int st = 0; st < 4; ++st)                                            \
      _Pragma("unroll")                                                       \
      for (int c = 0; c < 4; ++c)                                             \
        (OACC)[c] = __builtin_amdgcn_mfma_f32_16x16x16bf16_1k(                \
            pa[st], bv[st][c], (OACC)[c], 0, 0, 0);                           \
    __builtin_amdgcn_s_setprio(0);                                            \
  } while (0)

  STAGE(0, 0);

  for (int it = 0; it < ntB; ++it) {
    const int bi = it & 1;
    asm volatile("s_waitcnt vmcnt(0)" ::: "memory");
    __builtin_amdgcn_s_barrier();
    __builtin_amdgcn_sched_barrier(0);
    asm volatile("" ::: "memory");
    if (it + 1 < ntB) STAGE(bi ^ 1, (it + 1) << 6);

    if (it <= idqB) COMPUTE(q0B, aqB0, aqB1, oB, mB, lB, idqB);
    if (it <= idqA) COMPUTE(q0A, aqA0, aqA1, oA, mA, lA, idqA);
  }
#undef STAGE
#undef COMPUTE

  const int b = bh >> 4, h = bh & (NHEAD - 1);
#pragma unroll
  for (int r = 0; r < 4; ++r) {
    const float liB = __shfl(lB, (lane & 48) + grp * 4 + r);
    const float invB = 1.f / liB;
    const int nB = q0B + grp * 4 + r;
#pragma unroll
    for (int c = 0; c < 4; ++c)
      O[(size_t)(b * SEQ + nB) * HID + h * HD + c * 16 + lr] =
          f2bf(oB[c][r] * invB);
    const float liA = __shfl(lA, (lane & 48) + grp * 4 + r);
    const float invA = 1.f / liA;
    const int nA = q0A + grp * 4 + r;
#pragma unroll
    for (int c = 0; c < 4; ++c)
      O[(size_t)(b * SEQ + nA) * HID + h * HD + c * 16 + lr] =
          f2bf(oA[c][r] * invA);
  }
}

extern "C" void kernel_launch(void* const* d_in, const int* in_sizes, int n_in,
                              void* d_out, int out_size, void* d_ws, size_t ws_size,
                              hipStream_t stream) {
  const float* q  = (const float*)d_in[0];
  const float* k  = (const float*)d_in[1];
  const float* v  = (const float*)d_in[2];
  /* d_in[3] = mask: tril by construction -> causal handled structurally */
  const float* Wq = (const float*)d_in[4];
  const float* bq = (const float*)d_in[5];
  const float* Wk = (const float*)d_in[6];
  const float* bk = (const float*)d_in[7];
  const float* Wv = (const float*)d_in[8];
  const float* bv = (const float*)d_in[9];
  const float* Wp = (const float*)d_in[10];
  const float* bp = (const float*)d_in[11];
  float* out = (float*)d_out;

  char* ws = (char*)d_ws;
  const float qscale = 0.125f * 1.4426950408889634f;  // 1/sqrt(64) * log2(e)
  const dim3 ablk(8, NB * NHEAD);                     // paired q-tiles

  if (ws_size >= (56u << 20)) {
    // fused path (56 MiB): qb kb vb | Wcat(3x) Wpb | Qh Kh Vt ; AO aliases qb
    u16* qb   = (u16*)(ws);
    u16* kb   = (u16*)(ws + ( 8u << 20));
    u16* vb   = (u16*)(ws + (16u << 20));
    u16* Wcat = (u16*)(ws + (24u << 20));
    u16* Wpb  = (u16*)(ws + (30u << 20));
    u16* Qh   = (u16*)(ws + (32u << 20));
    u16* Kh   = (u16*)(ws + (40u << 20));
    u16* Vt   = (u16*)(ws + (48u << 20));
    u16* AO   = qb;

    conv_all<<<8192, 256, 0, stream>>>(q, k, v, Wq, Wk, Wv, Wp,
                                       qb, kb, vb, Wcat, Wpb);
    gemm128<0><<<dim3(24, 32), 256, 0, stream>>>(
        qb, kb, vb, Wcat, bq, bk, bv, Qh, Kh, Vt, nullptr, -1, qscale);
    attn_fwd<<<ablk, 512, 0, stream>>>(Qh, Kh, Vt, AO);
    gemm128<1><<<dim3(8, 32), 256, 0, stream>>>(
        AO, AO, AO, Wpb, bp, bp, bp, nullptr, nullptr, nullptr, out, 0, 1.f);
  } else {
    // fallback (40 MiB): cb | Wqb Wkb Wvb Wpb | Qh Kh Vt ; AO aliases cb
    u16* cb  = (u16*)(ws);
    u16* Wqb = (u16*)(ws + ( 8u << 20));
    u16* Wkb = (u16*)(ws + (10u << 20));
    u16* Wvb = (u16*)(ws + (12u << 20));
    u16* Wpb = (u16*)(ws + (14u << 20));
    u16* Qh  = (u16*)(ws + (16u << 20));
    u16* Kh  = (u16*)(ws + (24u << 20));
    u16* Vt  = (u16*)(ws + (32u << 20));
    u16* AO  = cb;
    const int NV_A = MROWS * HID / 8, NV_W = HID * HID / 8;

    conv_f32_bf16<<<NV_W / 256, 256, 0, stream>>>(Wq, Wqb, NV_W);
    conv_f32_bf16<<<NV_W / 256, 256, 0, stream>>>(Wk, Wkb, NV_W);
    conv_f32_bf16<<<NV_W / 256, 256, 0, stream>>>(Wv, Wvb, NV_W);
    conv_f32_bf16<<<NV_W / 256, 256, 0, stream>>>(Wp, Wpb, NV_W);

    conv_f32_bf16<<<NV_A / 256, 256, 0, stream>>>(q, cb, NV_A);
    gemm128<0><<<dim3(8, 32), 256, 0, stream>>>(
        cb, cb, cb, Wqb, bq, bk, bv, Qh, Kh, Vt, nullptr, 0, qscale);
    conv_f32_bf16<<<NV_A / 256, 256, 0, stream>>>(k, cb, NV_A);
    gemm128<0><<<dim3(8, 32), 256, 0, stream>>>(
        cb, cb, cb, Wkb, bq, bk, bv, Qh, Kh, Vt, nullptr, 1, qscale);
    conv_f32_bf16<<<NV_A / 256, 256, 0, stream>>>(v, cb, NV_A);
    gemm128<0><<<dim3(8, 32), 256, 0, stream>>>(
        cb, cb, cb, Wvb, bq, bk, bv, Qh, Kh, Vt, nullptr, 2, qscale);

    attn_fwd<<<ablk, 512, 0, stream>>>(Qh, Kh, Vt, AO);
    gemm128<1><<<dim3(8, 32), 256, 0, stream>>>(
        AO, AO, AO, Wpb, bp, bp, bp, nullptr, nullptr, nullptr, out, 0, 1.f);
  }
}